// Round 5
// baseline (848.649 us; speedup 1.0000x reference)
//
#include <hip/hip_runtime.h>
#include <hip/hip_fp16.h>

#define N_NODES 50000
#define N_EDGES 800000
#define N_OBS   4
#define HID     64
#define K_HOPS  5
#define ROW     (N_OBS * HID)   // 256 elements per node
#define NSCAN_BLKS ((N_NODES + 1023) / 1024)   // 49
#define NSLICE  8               // hid sliced into 8 x 8; slice-row = 4 obs x 8 hid = 32 f16 = 64B

typedef _Float16 f16x8 __attribute__((ext_vector_type(8)));
typedef _Float16 f16x4 __attribute__((ext_vector_type(4)));
typedef float    f32x4 __attribute__((ext_vector_type(4)));

// ---------------------------------------------------------------- zero
__global__ void zero_kernel(int* __restrict__ p, int n) {
    int i = blockIdx.x * blockDim.x + threadIdx.x;
    if (i < n) p[i] = 0;
}

// ---------------------------------------------------------------- histogram of dst
__global__ void hist_kernel(const int* __restrict__ dst, int* __restrict__ cnt) {
    int e = blockIdx.x * blockDim.x + threadIdx.x;
    if (e < N_EDGES) atomicAdd(&cnt[dst[e]], 1);
}

// ---------------------------------------------------------------- scan pass 1: per-block sums
__global__ __launch_bounds__(1024) void scan1_kernel(const int* __restrict__ counts,
                                                     int* __restrict__ bsum) {
    __shared__ int wsum[16];
    const int t = threadIdx.x, lane = t & 63, wid = t >> 6;
    int i = blockIdx.x * 1024 + t;
    int x = (i < N_NODES) ? counts[i] : 0;
    #pragma unroll
    for (int off = 32; off > 0; off >>= 1) x += __shfl_xor(x, off);
    if (lane == 0) wsum[wid] = x;
    __syncthreads();
    if (t == 0) {
        int s = 0;
        #pragma unroll
        for (int j = 0; j < 16; ++j) s += wsum[j];
        bsum[blockIdx.x] = s;
    }
}

// ---------------------------------------------------------------- scan pass 2: exclusive scan of block sums (1 wave)
__global__ void scan2_kernel(int* __restrict__ bsum) {
    const int t = threadIdx.x;   // 64 threads
    int v = (t < NSCAN_BLKS) ? bsum[t] : 0;
    int x = v;
    #pragma unroll
    for (int off = 1; off < 64; off <<= 1) {
        int y = __shfl_up(x, off);
        if (t >= off) x += y;
    }
    if (t < NSCAN_BLKS) bsum[t] = x - v;   // exclusive
}

// ---------------------------------------------------------------- scan pass 3: full offsets + cursor
__global__ __launch_bounds__(1024) void scan3_kernel(const int* __restrict__ counts,
                                                     const int* __restrict__ bsum,
                                                     int* __restrict__ offsets,
                                                     int* __restrict__ cursor) {
    __shared__ int wsum[16];
    __shared__ int wpre[16];
    const int t = threadIdx.x, lane = t & 63, wid = t >> 6;
    int i = blockIdx.x * 1024 + t;
    int v = (i < N_NODES) ? counts[i] : 0;
    int x = v;
    #pragma unroll
    for (int off = 1; off < 64; off <<= 1) {
        int y = __shfl_up(x, off);
        if (lane >= off) x += y;
    }
    if (lane == 63) wsum[wid] = x;
    __syncthreads();
    if (t < 16) {
        int p = 0;
        for (int j = 0; j < t; ++j) p += wsum[j];
        wpre[t] = p;
    }
    __syncthreads();
    int base = bsum[blockIdx.x];
    int incl = base + x + wpre[wid];
    if (i < N_NODES) {
        offsets[i + 1] = incl;
        cursor[i]      = incl - v;
    }
    if (i == 0) offsets[0] = 0;
}

// ---------------------------------------------------------------- scatter edges into CSR order, packed {f16 w | u16 src}
__global__ void scatter_kernel(const int* __restrict__ src, const int* __restrict__ dst,
                               const float* __restrict__ w, int* __restrict__ cursor,
                               unsigned int* __restrict__ ecmp) {
    int e = blockIdx.x * blockDim.x + threadIdx.x;
    if (e < N_EDGES) {
        int d = dst[e];
        int p = atomicAdd(&cursor[d], 1);
        __half hw = __float2half(w[e]);
        ecmp[p] = ((unsigned int)__half_as_ushort(hw) << 16) | (unsigned int)src[e];
    }
}

// ---------------------------------------------------------------- lift into sliced X[s][n][o][h3] f16
__global__ void lift_kernel(const float* __restrict__ nodes, const float* __restrict__ Wl,
                            const float* __restrict__ bl, __half* __restrict__ Xs) {
    int i = blockIdx.x * blockDim.x + threadIdx.x;   // 8B chunk = 4 f16
    const int total = N_NODES * ROW / 4;
    if (i >= total) return;
    int n   = i >> 6;
    int rem = i & 63;
    int o   = rem >> 4;
    int h4  = rem & 15;          // h = h4*4 .. +3
    int s   = h4 >> 1;
    int h3  = (h4 & 1) * 4;
    float sc = nodes[n * 4 + o];
    float4 wl = ((const float4*)Wl)[h4];
    float4 b  = ((const float4*)bl)[h4];
    f16x4 st;
    st[0] = (_Float16)(sc * wl.x + b.x);
    st[1] = (_Float16)(sc * wl.y + b.y);
    st[2] = (_Float16)(sc * wl.z + b.z);
    st[3] = (_Float16)(sc * wl.w + b.w);
    *(f16x4*)(Xs + (((size_t)s * N_NODES + n) * 4 + o) * 8 + h3) = st;
}

// ---------------------------------------------------------------- pack W_hop into MFMA B-fragment order (f16)
__global__ void packW_kernel(const float* __restrict__ W, _Float16* __restrict__ Bp) {
    int i = blockIdx.x * 256 + threadIdx.x;   // 0..4095
    if (i >= 4096) return;
    int j  = i & 7;
    int l  = (i >> 3) & 63;
    int ks = (i >> 9) & 1;
    int w  = i >> 10;
    int k   = ks * 32 + ((j >> 2) * 16) + ((l >> 4) * 4) + (j & 3);
    int col = w * 16 + (l & 15);
    Bp[i] = (_Float16)W[k * 64 + col];
}

// ---------------------------------------------------------------- pass 1: sliced gather
// slice = blockIdx & 7  (XCD locality heuristic; correctness-independent).
// Block = 4 waves x 4 nodes; wave processes its nodes' edges on a 64B row-slice.
// 8 edges per load instruction (8 lanes x 8B per edge), edge data shfl-broadcast.
__global__ __launch_bounds__(256) void gather_kernel(const int* __restrict__ offsets,
                                                     const unsigned int* __restrict__ ecmp,
                                                     const __half* __restrict__ Xs,
                                                     __half* __restrict__ Ag) {
    const int t = threadIdx.x;
    const int wid = t >> 6, lane = t & 63;
    const int s = blockIdx.x & 7;
    const int g = blockIdx.x >> 3;
    const int n0 = g * 16 + wid * 4;
    int offv = (lane < 5) ? offsets[n0 + lane] : 0;
    const int o0 = __shfl(offv, 0);
    const int o1 = __shfl(offv, 1);
    const int o2 = __shfl(offv, 2);
    const int o3 = __shfl(offv, 3);
    const int o4 = __shfl(offv, 4);
    const __half* Xb = Xs + (size_t)s * (N_NODES * 32);
    const int sub = lane & 7;    // 8B sub-chunk of the 64B slice-row
    const int ep  = lane >> 3;   // edge position within a round of 8

    float acc[4][4] = {{0.f}};

    for (int base = o0; base < o4; base += 64) {
        unsigned int pk = 0u;
        if (base + lane < o4) pk = ecmp[base + lane];
        const int bA0 = o0 - base, bA1 = o1 - base, bA2 = o2 - base,
                  bA3 = o3 - base, bA4 = o4 - base;
        int aa[5] = {bA0, bA1, bA2, bA3, bA4};
        #pragma unroll
        for (int nd = 0; nd < 4; ++nd) {
            int a = aa[nd];     if (a < 0) a = 0;
            int b = aa[nd + 1]; if (b > 64) b = 64;
            for (int r = a; r < b; r += 8) {
                int sl = r + ep;
                unsigned int p = (unsigned int)__shfl((int)pk, sl);
                float w = 0.f;
                if (sl < b) w = __half2float(__ushort_as_half((unsigned short)(p >> 16)));
                int srci = (int)(p & 0xffffu);
                f16x4 v = *(const f16x4*)(Xb + srci * 32 + sub * 4);
                acc[nd][0] += w * (float)v[0];
                acc[nd][1] += w * (float)v[1];
                acc[nd][2] += w * (float)v[2];
                acc[nd][3] += w * (float)v[3];
            }
        }
    }

    // reduce over the 8 edge positions (lane>>3); sub-chunk (lane&7) preserved
    #pragma unroll
    for (int m = 8; m < 64; m <<= 1) {
        #pragma unroll
        for (int nd = 0; nd < 4; ++nd) {
            #pragma unroll
            for (int j = 0; j < 4; ++j)
                acc[nd][j] += __shfl_xor(acc[nd][j], m);
        }
    }

    if (lane < 32) {
        int nd = lane >> 3;
        f16x4 st;
        st[0] = (_Float16)acc[nd][0];
        st[1] = (_Float16)acc[nd][1];
        st[2] = (_Float16)acc[nd][2];
        st[3] = (_Float16)acc[nd][3];
        *(f16x4*)(Ag + ((size_t)s * N_NODES + n0 + nd) * 32 + sub * 4) = st;
    }
}

// ---------------------------------------------------------------- pass 2: GEMM + bias + ReLU
// 16 nodes (64 rows) per block; stage sliced agg -> LDS; 8 MFMA per wave.
template<int LAST>
__global__ __launch_bounds__(256) void mm_kernel(const __half* __restrict__ Ag,
                                                 const _Float16* __restrict__ Bp,
                                                 const float* __restrict__ bias,
                                                 __half* __restrict__ Xs,
                                                 float* __restrict__ Fout) {
    __shared__ _Float16 As[64][72];
    const int t = threadIdx.x;
    const int wid = t >> 6, lane = t & 63;
    const int n0 = blockIdx.x * 16;

    // stage 16 nodes x 8 slices x 64B = 8KB
    #pragma unroll
    for (int it = 0; it < 2; ++it) {
        int c = t + 256 * it;      // 16B chunk id 0..511
        int s = c >> 6;
        int m = c & 63;            // 16 nodes x 4 chunks
        int nl = m >> 2, o = m & 3;
        f16x8 v = *(const f16x8*)(Ag + (((size_t)s * N_NODES + n0 + nl) * 4 + o) * 8);
        *(f16x8*)&As[nl * 4 + o][s * 8] = v;
    }
    __syncthreads();

    const int r15 = lane & 15, gq = lane >> 4;
    f16x8 b0 = *(const f16x8*)(Bp + ((size_t)(wid * 2 + 0) * 64 + lane) * 8);
    f16x8 b1 = *(const f16x8*)(Bp + ((size_t)(wid * 2 + 1) * 64 + lane) * 8);
    const float bv = bias[wid * 16 + r15];
    const int h = wid * 16 + r15;

    #pragma unroll
    for (int rg = 0; rg < 4; ++rg) {
        const int row = rg * 16 + r15;
        f16x8 a0, a1;
        ((f16x4*)&a0)[0] = *(const f16x4*)&As[row][ 0 + 4 * gq];
        ((f16x4*)&a0)[1] = *(const f16x4*)&As[row][16 + 4 * gq];
        ((f16x4*)&a1)[0] = *(const f16x4*)&As[row][32 + 4 * gq];
        ((f16x4*)&a1)[1] = *(const f16x4*)&As[row][48 + 4 * gq];
        f32x4 c4 = {0.f, 0.f, 0.f, 0.f};
        c4 = __builtin_amdgcn_mfma_f32_16x16x32_f16(a0, b0, c4, 0, 0, 0);
        c4 = __builtin_amdgcn_mfma_f32_16x16x32_f16(a1, b1, c4, 0, 0, 0);
        #pragma unroll
        for (int j = 0; j < 4; ++j) {
            int r_abs = rg * 16 + gq * 4 + j;   // output row
            int nl = r_abs >> 2, o = r_abs & 3;
            float v = fmaxf(c4[j] + bv, 0.f);
            if (LAST) {
                Fout[((size_t)(n0 + nl) * 4 + o) * 64 + h] = v;
            } else {
                int sl = h >> 3, h3 = h & 7;
                Xs[(((size_t)sl * N_NODES + n0 + nl) * 4 + o) * 8 + h3] = __float2half(v);
            }
        }
    }
}

// ---------------------------------------------------------------- launch
extern "C" void kernel_launch(void* const* d_in, const int* in_sizes, int n_in,
                              void* d_out, int out_size, void* d_ws, size_t ws_size,
                              hipStream_t stream) {
    const float* nodes   = (const float*)d_in[0];
    const int*   esrc    = (const int*)d_in[1];
    const int*   edst    = (const int*)d_in[2];
    const float* eweight = (const float*)d_in[3];
    const float* W_lift  = (const float*)d_in[4];
    const float* b_lift  = (const float*)d_in[5];
    const float* W_hop   = (const float*)d_in[6];
    const float* b_hop   = (const float*)d_in[7];

    char* ws = (char*)d_ws;
    __half*       X    = (__half*)(ws);                      // 25,600,000 B (sliced)
    __half*       AGG  = (__half*)(ws + 25600000);           // 25,600,000 B (sliced)
    unsigned int* ECMP = (unsigned int*)(ws + 51200000);     //  3,200,000 B
    int*          OFF  = (int*)(ws + 54400000);              //    200,064 B
    int*          CUR  = (int*)(ws + 54600064);              //    200,000 B
    int*          CNT  = (int*)(ws + 54800064);              //    200,000 B
    int*          BSUM = (int*)(ws + 55000064);              //        256 B
    _Float16*     BP   = (_Float16*)(ws + 55000320);         //      8,192 B

    // CSR build
    zero_kernel<<<(N_NODES + 255) / 256, 256, 0, stream>>>(CNT, N_NODES);
    hist_kernel<<<(N_EDGES + 255) / 256, 256, 0, stream>>>(edst, CNT);
    scan1_kernel<<<NSCAN_BLKS, 1024, 0, stream>>>(CNT, BSUM);
    scan2_kernel<<<1, 64, 0, stream>>>(BSUM);
    scan3_kernel<<<NSCAN_BLKS, 1024, 0, stream>>>(CNT, BSUM, OFF, CUR);
    scatter_kernel<<<(N_EDGES + 255) / 256, 256, 0, stream>>>(esrc, edst, eweight, CUR, ECMP);

    // lift -> sliced f16 X ; pack W_hop -> MFMA B fragments
    lift_kernel<<<(N_NODES * ROW / 4 + 255) / 256, 256, 0, stream>>>(nodes, W_lift, b_lift, X);
    packW_kernel<<<16, 256, 0, stream>>>(W_hop, BP);

    // hops: sliced gather (pass 1) + GEMM (pass 2); X updated in place by pass 2
    const int gGrid  = (N_NODES / 16) * NSLICE;   // 3125 * 8 = 25000
    const int mmGrid = N_NODES / 16;              // 3125
    for (int hop = 0; hop < K_HOPS; ++hop) {
        gather_kernel<<<gGrid, 256, 0, stream>>>(OFF, ECMP, X, AGG);
        if (hop == K_HOPS - 1) {
            mm_kernel<1><<<mmGrid, 256, 0, stream>>>(AGG, BP, b_hop, nullptr, (float*)d_out);
        } else {
            mm_kernel<0><<<mmGrid, 256, 0, stream>>>(AGG, BP, b_hop, X, nullptr);
        }
    }
}

// Round 7
// 730.738 us; speedup vs baseline: 1.1614x; 1.1614x over previous
//
#include <hip/hip_runtime.h>
#include <hip/hip_fp16.h>

#define N_NODES 50000
#define N_EDGES 800000
#define N_OBS   4
#define HID     64
#define K_HOPS  5
#define ROW     (N_OBS * HID)   // 256 elements per node
#define NSCAN_BLKS ((N_NODES + 1023) / 1024)   // 49
#define NSLICE  8               // hid sliced 8x8: slice-row = 4 obs x 8 hid = 32 f16 = 64B

typedef _Float16 f16x8 __attribute__((ext_vector_type(8)));
typedef _Float16 f16x4 __attribute__((ext_vector_type(4)));
typedef float    f32x4 __attribute__((ext_vector_type(4)));

// ---------------------------------------------------------------- zero
__global__ void zero_kernel(int* __restrict__ p, int n) {
    int i = blockIdx.x * blockDim.x + threadIdx.x;
    if (i < n) p[i] = 0;
}

// ---------------------------------------------------------------- histogram of dst
__global__ void hist_kernel(const int* __restrict__ dst, int* __restrict__ cnt) {
    int e = blockIdx.x * blockDim.x + threadIdx.x;
    if (e < N_EDGES) atomicAdd(&cnt[dst[e]], 1);
}

// ---------------------------------------------------------------- scan pass 1: per-block sums
__global__ __launch_bounds__(1024) void scan1_kernel(const int* __restrict__ counts,
                                                     int* __restrict__ bsum) {
    __shared__ int wsum[16];
    const int t = threadIdx.x, lane = t & 63, wid = t >> 6;
    int i = blockIdx.x * 1024 + t;
    int x = (i < N_NODES) ? counts[i] : 0;
    #pragma unroll
    for (int off = 32; off > 0; off >>= 1) x += __shfl_xor(x, off);
    if (lane == 0) wsum[wid] = x;
    __syncthreads();
    if (t == 0) {
        int s = 0;
        #pragma unroll
        for (int j = 0; j < 16; ++j) s += wsum[j];
        bsum[blockIdx.x] = s;
    }
}

// ---------------------------------------------------------------- scan pass 2: exclusive scan of block sums (1 wave)
__global__ void scan2_kernel(int* __restrict__ bsum) {
    const int t = threadIdx.x;   // 64 threads
    int v = (t < NSCAN_BLKS) ? bsum[t] : 0;
    int x = v;
    #pragma unroll
    for (int off = 1; off < 64; off <<= 1) {
        int y = __shfl_up(x, off);
        if (t >= off) x += y;
    }
    if (t < NSCAN_BLKS) bsum[t] = x - v;   // exclusive
}

// ---------------------------------------------------------------- scan pass 3: full offsets + cursor
__global__ __launch_bounds__(1024) void scan3_kernel(const int* __restrict__ counts,
                                                     const int* __restrict__ bsum,
                                                     int* __restrict__ offsets,
                                                     int* __restrict__ cursor) {
    __shared__ int wsum[16];
    __shared__ int wpre[16];
    const int t = threadIdx.x, lane = t & 63, wid = t >> 6;
    int i = blockIdx.x * 1024 + t;
    int v = (i < N_NODES) ? counts[i] : 0;
    int x = v;
    #pragma unroll
    for (int off = 1; off < 64; off <<= 1) {
        int y = __shfl_up(x, off);
        if (lane >= off) x += y;
    }
    if (lane == 63) wsum[wid] = x;
    __syncthreads();
    if (t < 16) {
        int p = 0;
        for (int j = 0; j < t; ++j) p += wsum[j];
        wpre[t] = p;
    }
    __syncthreads();
    int base = bsum[blockIdx.x];
    int incl = base + x + wpre[wid];
    if (i < N_NODES) {
        offsets[i + 1] = incl;
        cursor[i]      = incl - v;
    }
    if (i == 0) offsets[0] = 0;
}

// ---------------------------------------------------------------- scatter edges into CSR order, packed {f16 w | u16 src}
__global__ void scatter_kernel(const int* __restrict__ src, const int* __restrict__ dst,
                               const float* __restrict__ w, int* __restrict__ cursor,
                               unsigned int* __restrict__ ecmp) {
    int e = blockIdx.x * blockDim.x + threadIdx.x;
    if (e < N_EDGES) {
        int d = dst[e];
        int p = atomicAdd(&cursor[d], 1);
        __half hw = __float2half(w[e]);
        ecmp[p] = ((unsigned int)__half_as_ushort(hw) << 16) | (unsigned int)src[e];
    }
}

// ---------------------------------------------------------------- lift into sliced X[s][n][o][h3] f16
__global__ void lift_kernel(const float* __restrict__ nodes, const float* __restrict__ Wl,
                            const float* __restrict__ bl, __half* __restrict__ Xs) {
    int i = blockIdx.x * blockDim.x + threadIdx.x;   // 8B chunk = 4 f16
    const int total = N_NODES * ROW / 4;
    if (i >= total) return;
    int n   = i >> 6;
    int rem = i & 63;
    int o   = rem >> 4;
    int h4  = rem & 15;          // h = h4*4 .. +3
    int s   = h4 >> 1;
    int h3  = (h4 & 1) * 4;
    float sc = nodes[n * 4 + o];
    float4 wl = ((const float4*)Wl)[h4];
    float4 b  = ((const float4*)bl)[h4];
    f16x4 st;
    st[0] = (_Float16)(sc * wl.x + b.x);
    st[1] = (_Float16)(sc * wl.y + b.y);
    st[2] = (_Float16)(sc * wl.z + b.z);
    st[3] = (_Float16)(sc * wl.w + b.w);
    *(f16x4*)(Xs + (((size_t)s * N_NODES + n) * 4 + o) * 8 + h3) = st;
}

// ---------------------------------------------------------------- pack W_hop into MFMA B-fragment order (f16)
__global__ void packW_kernel(const float* __restrict__ W, _Float16* __restrict__ Bp) {
    int i = blockIdx.x * 256 + threadIdx.x;   // 0..4095
    if (i >= 4096) return;
    int j  = i & 7;
    int l  = (i >> 3) & 63;
    int ks = (i >> 9) & 1;
    int w  = i >> 10;
    int k   = ks * 32 + ((j >> 2) * 16) + ((l >> 4) * 4) + (j & 3);
    int col = w * 16 + (l & 15);
    Bp[i] = (_Float16)W[k * 64 + col];
}

// ---------------------------------------------------------------- pass 1: sliced gather, output-element ownership.
// slice = blockIdx & 7 (XCD affinity; proven by R5's FETCH collapse).
// Block = 4 waves x 4 nodes x 16 lanes = 16 nodes per block, one slice.
// Lane owns 2 consecutive f16 elements of its node's 64B slice-row; all 4
// node-groups of a wave stream their edge lists simultaneously via per-lane
// shfl slots. No cross-lane reduce, no atomics.
__global__ __launch_bounds__(256) void gather_kernel(const int* __restrict__ offsets,
                                                     const unsigned int* __restrict__ ecmp,
                                                     const __half* __restrict__ Xs,
                                                     __half* __restrict__ Ag) {
    const int t = threadIdx.x;
    const int wid = t >> 6, lane = t & 63;
    const int s = blockIdx.x & 7;
    const int g = blockIdx.x >> 3;           // node group 0..3124
    const int n0 = g * 16 + wid * 4;
    const int grp = lane >> 4;               // node within wave (0..3)
    const int el  = lane & 15;               // element-pair within 32-f16 row
    const int n = n0 + grp;
    const int sN = offsets[n], eN = offsets[n + 1];
    const int o0 = __shfl(sN, 0);
    const int o4 = __shfl(eN, 63);
    const __half* Xb = Xs + (size_t)s * ((size_t)N_NODES * 32);

    float ax = 0.f, ay = 0.f;

    for (int base = o0; base < o4; base += 64) {
        unsigned int pk = 0u;                // src=0, w=+0 for pad lanes
        if (base + lane < o4) pk = ecmp[base + lane];
        int lo = sN - base; if (lo < 0) lo = 0;
        int hi = eN - base; if (hi > 64) hi = 64;
        const int m = hi - lo;               // this group's edges in chunk
        for (int q = 0; ; ++q) {
            bool act = q < m;
            if (!__any(act)) break;
            int r = lo + q;
            if (r > 63) r = 63;
            unsigned int p = (unsigned int)__shfl((int)pk, r);
            float w = act ? __half2float(__ushort_as_half((unsigned short)(p >> 16))) : 0.f;
            int src = (int)(p & 0xffffu);
            __half2 h2 = *(const __half2*)(Xb + src * 32 + el * 2);
            float2 f2 = __half22float2(h2);
            ax += w * f2.x;
            ay += w * f2.y;
        }
    }

    __half2 o = __float22half2_rn(make_float2(ax, ay));
    *(__half2*)(Ag + ((size_t)s * N_NODES + n) * 32 + el * 2) = o;
}

// ---------------------------------------------------------------- pass 2: GEMM + bias + ReLU
// 16 nodes (64 rows) per block; stage sliced agg -> LDS; 8 MFMA per wave.
template<int LAST>
__global__ __launch_bounds__(256) void mm_kernel(const __half* __restrict__ Ag,
                                                 const _Float16* __restrict__ Bp,
                                                 const float* __restrict__ bias,
                                                 __half* __restrict__ Xs,
                                                 float* __restrict__ Fout) {
    __shared__ _Float16 As[64][72];
    const int t = threadIdx.x;
    const int wid = t >> 6, lane = t & 63;
    const int n0 = blockIdx.x * 16;

    // stage 16 nodes x 8 slices x 64B = 8KB
    #pragma unroll
    for (int it = 0; it < 2; ++it) {
        int c = t + 256 * it;      // 16B chunk id 0..511
        int s = c >> 6;
        int m = c & 63;            // 16 nodes x 4 chunks
        int nl = m >> 2, o = m & 3;
        f16x8 v = *(const f16x8*)(Ag + (((size_t)s * N_NODES + n0 + nl) * 4 + o) * 8);
        *(f16x8*)&As[nl * 4 + o][s * 8] = v;
    }
    __syncthreads();

    const int r15 = lane & 15, gq = lane >> 4;
    f16x8 b0 = *(const f16x8*)(Bp + ((size_t)(wid * 2 + 0) * 64 + lane) * 8);
    f16x8 b1 = *(const f16x8*)(Bp + ((size_t)(wid * 2 + 1) * 64 + lane) * 8);
    const float bv = bias[wid * 16 + r15];
    const int h = wid * 16 + r15;

    #pragma unroll
    for (int rg = 0; rg < 4; ++rg) {
        const int row = rg * 16 + r15;
        f16x8 a0, a1;
        ((f16x4*)&a0)[0] = *(const f16x4*)&As[row][ 0 + 4 * gq];
        ((f16x4*)&a0)[1] = *(const f16x4*)&As[row][16 + 4 * gq];
        ((f16x4*)&a1)[0] = *(const f16x4*)&As[row][32 + 4 * gq];
        ((f16x4*)&a1)[1] = *(const f16x4*)&As[row][48 + 4 * gq];
        f32x4 c4 = {0.f, 0.f, 0.f, 0.f};
        c4 = __builtin_amdgcn_mfma_f32_16x16x32_f16(a0, b0, c4, 0, 0, 0);
        c4 = __builtin_amdgcn_mfma_f32_16x16x32_f16(a1, b1, c4, 0, 0, 0);
        #pragma unroll
        for (int j = 0; j < 4; ++j) {
            int r_abs = rg * 16 + gq * 4 + j;   // output row
            int nl = r_abs >> 2, o = r_abs & 3;
            float v = fmaxf(c4[j] + bv, 0.f);
            if (LAST) {
                Fout[((size_t)(n0 + nl) * 4 + o) * 64 + h] = v;
            } else {
                int sl = h >> 3, h3 = h & 7;
                Xs[(((size_t)sl * N_NODES + n0 + nl) * 4 + o) * 8 + h3] = __float2half(v);
            }
        }
    }
}

// ---------------------------------------------------------------- launch
extern "C" void kernel_launch(void* const* d_in, const int* in_sizes, int n_in,
                              void* d_out, int out_size, void* d_ws, size_t ws_size,
                              hipStream_t stream) {
    const float* nodes   = (const float*)d_in[0];
    const int*   esrc    = (const int*)d_in[1];
    const int*   edst    = (const int*)d_in[2];
    const float* eweight = (const float*)d_in[3];
    const float* W_lift  = (const float*)d_in[4];
    const float* b_lift  = (const float*)d_in[5];
    const float* W_hop   = (const float*)d_in[6];
    const float* b_hop   = (const float*)d_in[7];

    char* ws = (char*)d_ws;
    __half*       X    = (__half*)(ws);                      // 25,600,000 B (sliced)
    __half*       AGG  = (__half*)(ws + 25600000);           // 25,600,000 B (sliced)
    unsigned int* ECMP = (unsigned int*)(ws + 51200000);     //  3,200,000 B
    int*          OFF  = (int*)(ws + 54400000);              //    200,064 B
    int*          CUR  = (int*)(ws + 54600064);              //    200,000 B
    int*          CNT  = (int*)(ws + 54800064);              //    200,000 B
    int*          BSUM = (int*)(ws + 55000064);              //        256 B
    _Float16*     BP   = (_Float16*)(ws + 55000320);         //      8,192 B

    // CSR build
    zero_kernel<<<(N_NODES + 255) / 256, 256, 0, stream>>>(CNT, N_NODES);
    hist_kernel<<<(N_EDGES + 255) / 256, 256, 0, stream>>>(edst, CNT);
    scan1_kernel<<<NSCAN_BLKS, 1024, 0, stream>>>(CNT, BSUM);
    scan2_kernel<<<1, 64, 0, stream>>>(BSUM);
    scan3_kernel<<<NSCAN_BLKS, 1024, 0, stream>>>(CNT, BSUM, OFF, CUR);
    scatter_kernel<<<(N_EDGES + 255) / 256, 256, 0, stream>>>(esrc, edst, eweight, CUR, ECMP);

    // lift -> sliced f16 X ; pack W_hop -> MFMA B fragments
    lift_kernel<<<(N_NODES * ROW / 4 + 255) / 256, 256, 0, stream>>>(nodes, W_lift, b_lift, X);
    packW_kernel<<<16, 256, 0, stream>>>(W_hop, BP);

    // hops: sliced gather (pass 1) + GEMM (pass 2); X updated in place by pass 2
    const int gGrid  = (N_NODES / 16) * NSLICE;   // 3125 * 8 = 25000 (16 nodes/block)
    const int mmGrid = N_NODES / 16;              // 3125
    for (int hop = 0; hop < K_HOPS; ++hop) {
        gather_kernel<<<gGrid, 256, 0, stream>>>(OFF, ECMP, X, AGG);
        if (hop == K_HOPS - 1) {
            mm_kernel<1><<<mmGrid, 256, 0, stream>>>(AGG, BP, b_hop, nullptr, (float*)d_out);
        } else {
            mm_kernel<0><<<mmGrid, 256, 0, stream>>>(AGG, BP, b_hop, X, nullptr);
        }
    }
}